// Round 21
// baseline (156.843 us; speedup 1.0000x reference)
//
#include <hip/hip_runtime.h>

#define Bn 8
#define Hn 8
#define Tn 1024
#define Dn 128

typedef __attribute__((ext_vector_type(8))) short bf16x8;
typedef __attribute__((ext_vector_type(4))) float f32x4;

typedef __attribute__((address_space(3))) unsigned int lds_as_t;
typedef __attribute__((address_space(1))) const unsigned int glb_as_t;

static __device__ __forceinline__ void gload_lds16(const unsigned short* g, unsigned short* l) {
    __builtin_amdgcn_global_load_lds((glb_as_t*)g, (lds_as_t*)l, 16, 0, 0);
}
static __device__ __forceinline__ void gload_lds16b(const char* g, char* l) {
    __builtin_amdgcn_global_load_lds((glb_as_t*)g, (lds_as_t*)l, 16, 0, 0);
}

static __device__ __forceinline__ unsigned short f2bf(float f) {
    union { float f; unsigned int u; } v; v.f = f;
    unsigned int u = v.u;
    return (unsigned short)((u + 0x7FFFu + ((u >> 16) & 1u)) >> 16);
}
static __device__ __forceinline__ int pack_bf16_trunc(float lo, float hi) {
    union { float f; unsigned int u; } a, b;
    a.f = lo; b.f = hi;
    return (int)__builtin_amdgcn_perm(b.u, a.u, 0x07060302u);
}

// ---------------- dispatch 1: fused prep + QKV GEMM (R20, unchanged) ----------------
__global__ __launch_bounds__(256, 2) void qkv_kernel(
    const float* __restrict__ x,  const float* __restrict__ Wq,
    const float* __restrict__ Wk, const float* __restrict__ Wv,
    const float* __restrict__ Wu, const int* __restrict__ mask,
    const float* __restrict__ bu, float* __restrict__ out,
    unsigned short* __restrict__ wuF, unsigned long long* __restrict__ mbits,
    char* __restrict__ Q, char* __restrict__ K, unsigned short* __restrict__ Vt)
{
    const int bx = blockIdx.x, by = blockIdx.y;
    const int tid  = threadIdx.x;
    const int wave = tid >> 6;
    const int lane = tid & 63;
    const int l16  = lane & 15;
    const int quad = lane >> 4;
    const int wm = wave & 1, wn = wave >> 1;
    const int which = by >> 3;
    const int h_ = by & 7;
    const int bid = h_ * 64 + bx;

    __shared__ __align__(16) unsigned short As[128 * 128];
    __shared__ __align__(16) unsigned short Bs[128 * 128];

    // ---- side work ----
    if (which == 0) {
        int base = (bid * 4 + wave) * 8;
#pragma unroll
        for (int i = 0; i < 8; i++) {
            int widx = base + i;
            int row = widx >> 4, kt = widx & 15;
            int v = mask[row * Tn + kt * 64 + lane];
            unsigned long long b = __ballot(v != 0);
            if (lane == 0) mbits[kt * Tn + row] = b;
        }
    } else if (which == 1) {
        if (tid < 32) {
            int id = bid * 32 + tid;
            int lane_ = id & 63;
            int fid = id >> 6;
            int nt = fid & 7, ks = (fid >> 3) & 3, h = fid >> 5;
            int row = nt * 16 + (lane_ & 15);
            int col = h * 128 + ks * 32 + (lane_ >> 4) * 8;
            const float* src = Wu + (size_t)row * 1024 + col;
            float4 f0 = *(const float4*)(src);
            float4 f1 = *(const float4*)(src + 4);
            unsigned short o[8];
            o[0] = f2bf(f0.x); o[1] = f2bf(f0.y); o[2] = f2bf(f0.z); o[3] = f2bf(f0.w);
            o[4] = f2bf(f1.x); o[5] = f2bf(f1.y); o[6] = f2bf(f1.z); o[7] = f2bf(f1.w);
            *(ushort4*)(wuF + (size_t)id * 8)     = *(ushort4*)&o[0];
            *(ushort4*)(wuF + (size_t)id * 8 + 4) = *(ushort4*)&o[4];
        }
    } else {
        int f4 = bid * 512 + tid * 2;
#pragma unroll
        for (int i = 0; i < 2; i++)
            ((float4*)out)[f4 + i] = ((const float4*)bu)[(f4 + i) & 31];
    }

    // ---- coalesced staging: fp32 -> bf16 -> swizzled LDS image ----
    const float* wsel = (which == 0) ? Wq : (which == 1) ? Wk : Wv;
    const float* Asrc = x + (size_t)(bx * 128) * 128;
    const float* Bsrc = wsel + (size_t)(h_ * 128) * 128;

#pragma unroll
    for (int it = 0; it < 16; it++) {
        int idx = it * 1024 + tid * 4;
        int row = idx >> 7, col = idx & 127;
        int dst = row * 128 + ((((col >> 3) ^ (row & 15)) << 3) | (col & 7));
        float4 fa = *(const float4*)(Asrc + idx);
        ushort4 oa;
        oa.x = f2bf(fa.x); oa.y = f2bf(fa.y); oa.z = f2bf(fa.z); oa.w = f2bf(fa.w);
        *(ushort4*)(&As[dst]) = oa;
        float4 fb = *(const float4*)(Bsrc + idx);
        ushort4 ob;
        ob.x = f2bf(fb.x); ob.y = f2bf(fb.y); ob.z = f2bf(fb.z); ob.w = f2bf(fb.w);
        *(ushort4*)(&Bs[dst]) = ob;
    }
    __syncthreads();

    // ---- MFMA body ----
    bf16x8 a[4][4];
#pragma unroll
    for (int mt = 0; mt < 4; mt++) {
        int row = wm * 64 + mt * 16 + l16;
#pragma unroll
        for (int ks = 0; ks < 4; ks++)
            a[mt][ks] = *(const bf16x8*)(&As[row * 128 + (((ks * 4 + quad) ^ (row & 15)) << 3)]);
    }

    f32x4 acc[4][4];
#pragma unroll
    for (int nt = 0; nt < 4; nt++) {
        int row = wn * 64 + nt * 16 + l16;
        bf16x8 b4[4];
#pragma unroll
        for (int ks = 0; ks < 4; ks++)
            b4[ks] = *(const bf16x8*)(&Bs[row * 128 + (((ks * 4 + quad) ^ (row & 15)) << 3)]);
#pragma unroll
        for (int mt = 0; mt < 4; mt++) {
            f32x4 c = {0.f, 0.f, 0.f, 0.f};
#pragma unroll
            for (int ks = 0; ks < 4; ks++)
                c = __builtin_amdgcn_mfma_f32_16x16x32_bf16(a[mt][ks], b4[ks], c, 0, 0, 0);
            acc[mt][nt] = c;
        }
    }

    const int b_ = bx >> 3;
    if (which < 2) {
        __syncthreads();
        char* escr = (char*)As;
#pragma unroll
        for (int mt = 0; mt < 4; mt++) {
#pragma unroll
            for (int nt = 0; nt < 4; nt++) {
                int w = __builtin_amdgcn_cvt_pk_fp8_f32(acc[mt][nt][0], acc[mt][nt][1], 0, false);
                w = __builtin_amdgcn_cvt_pk_fp8_f32(acc[mt][nt][2], acc[mt][nt][3], w, true);
                int col = wn * 64 + nt * 16 + l16;
#pragma unroll
                for (int r = 0; r < 4; r++)
                    escr[(wm * 64 + mt * 16 + quad * 4 + r) * 144 + col] = (char)(w >> (8 * r));
            }
        }
        __syncthreads();
        int row = tid >> 1;
        int t_in = (bx & 7) * 128 + row;
        char* dst = (which == 0) ? Q : K;
        size_t rowbase = ((size_t)((b_ * Hn + h_) * Tn + t_in)) * 128;
#pragma unroll
        for (int i = 0; i < 4; i++) {
            int c = (tid & 1) * 4 + i;
            int4 v = *(const int4*)(escr + row * 144 + c * 16);
            int cc = (which == 1) ? (c ^ (row & 7)) : c;
            *(int4*)(dst + rowbase + cc * 16) = v;
        }
    } else {
#pragma unroll
        for (int mt = 0; mt < 4; mt++) {
            int m_base = bx * 128 + wm * 64 + mt * 16 + quad * 4;
            int t0 = m_base & 1023;
#pragma unroll
            for (int nt = 0; nt < 4; nt++) {
                int e_ = wn * 64 + nt * 16 + l16;
                int kt_ = t0 >> 6, tc0 = t0 & 63;
                size_t off = ((((size_t)(b_ * Hn + h_) * 16 + kt_) * 128 + e_) << 6)
                           + ((((tc0 >> 3) ^ (e_ & 7)) << 3) | (tc0 & 7));
                ushort4 v4;
                v4.x = f2bf(acc[mt][nt][0]); v4.y = f2bf(acc[mt][nt][1]);
                v4.z = f2bf(acc[mt][nt][2]); v4.w = f2bf(acc[mt][nt][3]);
                *(ushort4*)(Vt + off) = v4;
            }
        }
    }
}

// ---------------- dispatch 2: flash attention, 64-row q-tiles, backfilled ----------------
// grid 1024: qt = 15 - (id>>6) (long tiles dispatch first, short tiles backfill),
// bh = id&63 (same-bh blocks share id%8 -> same XCD -> K/V L2-resident).
// 3 blocks/CU (LDS 48KB): retiring short blocks are replaced -> sustained occupancy.
__global__ __launch_bounds__(256, 3) void attn_kernel(
    const char* __restrict__ Q,               // fp8 [64][1024][128] plain
    const char* __restrict__ K,               // fp8 [64][1024][128] chunk swizzle c^(t&7)
    const unsigned short* __restrict__ Vt,    // bf16 [64][16][128][64] tiled+swizzled
    const unsigned long long* __restrict__ mbits, // [16][1024] transposed
    const unsigned short* __restrict__ wuF,   // [((h*4+ks)*8+nt)*64+lane][8]
    float* __restrict__ out)                  // [8192][128] fp32, bias-preset
{
    const int id   = blockIdx.x;
    const int qt   = 15 - (id >> 6);
    const int bh   = id & 63;
    const int wave = threadIdx.x >> 6;
    const int lane = threadIdx.x & 63;
    const int l16  = lane & 15;
    const int quad = lane >> 4;

    __shared__ __align__(16) char kbuf[2][64 * 128];            // 8 KB each
    __shared__ __align__(16) unsigned short vbuf[2][128 * 64];  // 16 KB each

    const char* Qb = Q  + (size_t)bh * Tn * Dn;
    const char* Kb = K  + (size_t)bh * Tn * Dn;
    const unsigned short* Vb = Vt + (size_t)bh * (16 * 128 * 64);

    const int q0 = qt * 64 + wave * 16;
    const int qrow = q0 + quad * 4;

    long qf[4];
#pragma unroll
    for (int ks = 0; ks < 4; ks++)
        qf[ks] = *(const long*)(Qb + (size_t)(q0 + l16) * 128 + ks * 32 + quad * 8);

    bf16x8 ones;
#pragma unroll
    for (int j = 0; j < 8; j++) ones[j] = (short)0x3F80;

    f32x4 o[8];
#pragma unroll
    for (int et = 0; et < 8; et++) o[et] = (f32x4){0.f, 0.f, 0.f, 0.f};
    f32x4 lacc = {0.f, 0.f, 0.f, 0.f};

    const float SL = 0.12752041570284543f;  // 1/sqrt(128) * log2(e)

    const int idx0 = (l16 << 2) + ((quad & 1) << 7);
    const int idx1 = idx0 + 64;
    const bool hiQ = (quad >> 1) != 0;

#pragma unroll
    for (int i = 0; i < 2; i++) {
        int base = (wave * 2 + i) * 1024;
        gload_lds16b(Kb + base + lane * 16, &kbuf[0][base]);
    }
#pragma unroll
    for (int i = 0; i < 4; i++) {
        int base = (wave * 4 + i) * 512;
        gload_lds16(Vb + base + lane * 8, &vbuf[0][base]);
    }

    for (int kt = 0; kt <= qt; kt++) {
        const int cur = kt & 1;
        __syncthreads();

        if (kt < qt) {
            const char* Kg = Kb + (kt + 1) * (64 * 128);
            const unsigned short* Vg = Vb + (kt + 1) * (128 * 64);
#pragma unroll
            for (int i = 0; i < 2; i++) {
                int base = (wave * 2 + i) * 1024;
                gload_lds16b(Kg + base + lane * 16, &kbuf[cur ^ 1][base]);
            }
#pragma unroll
            for (int i = 0; i < 4; i++) {
                int base = (wave * 4 + i) * 512;
                gload_lds16(Vg + base + lane * 8, &vbuf[cur ^ 1][base]);
            }
        }

        const unsigned long long mw = mbits[kt * Tn + q0 + l16];

        // S^T = K·Q^T (fp8)
        f32x4 s[4];
#pragma unroll
        for (int nt = 0; nt < 4; nt++) {
            int row = nt * 16 + l16;
            long a4[4];
#pragma unroll
            for (int ks = 0; ks < 4; ks++) {
                int c = ks * 2 + (quad >> 1);
                a4[ks] = *(const long*)(&kbuf[cur][row * 128 + (((c ^ (row & 7)) << 4) | ((quad & 1) << 3))]);
            }
            f32x4 c = {0.f, 0.f, 0.f, 0.f};
#pragma unroll
            for (int ks = 0; ks < 4; ks++)
                c = __builtin_amdgcn_mfma_f32_16x16x32_fp8_fp8(a4[ks], qf[ks], c, 0, 0, 0);
            s[nt] = c;
        }

        // p = live ? exp2(s*SL) : 0, packed (truncating) to bf16 pairs
        const int kc0 = kt * 64;
        const int qglob = q0 + l16;
        int w[4][2];
#pragma unroll
        for (int nt = 0; nt < 4; nt++) {
            float pv[4];
#pragma unroll
            for (int r = 0; r < 4; r++) {
                int bit = nt * 16 + quad * 4 + r;
                bool live = ((mw >> bit) & 1ULL) && (kc0 + bit <= qglob);
                pv[r] = live ? __builtin_amdgcn_exp2f(s[nt][r] * SL) : 0.f;
            }
            w[nt][0] = pack_bf16_trunc(pv[0], pv[1]);
            w[nt][1] = pack_bf16_trunc(pv[2], pv[3]);
        }

        bf16x8 pf[2];
#pragma unroll
        for (int k2 = 0; k2 < 2; k2++) {
            union { int i[4]; bf16x8 v; } u;
#pragma unroll
            for (int d = 0; d < 4; d++) {
                int idx = (d < 2) ? idx0 : idx1;
                int va = __builtin_amdgcn_ds_bpermute(idx, w[2 * k2][d & 1]);
                int vb = __builtin_amdgcn_ds_bpermute(idx, w[2 * k2 + 1][d & 1]);
                u.i[d] = hiQ ? vb : va;
            }
            pf[k2] = u.v;
        }

#pragma unroll
        for (int k2 = 0; k2 < 2; k2++)
            lacc = __builtin_amdgcn_mfma_f32_16x16x32_bf16(pf[k2], ones, lacc, 0, 0, 0);

#pragma unroll
        for (int et = 0; et < 8; et++) {
            int row = et * 16 + l16;
#pragma unroll
            for (int k2 = 0; k2 < 2; k2++) {
                bf16x8 b = *(const bf16x8*)(&vbuf[cur][row * 64 + (((k2 * 4 + quad) ^ (l16 & 7)) << 3)]);
                o[et] = __builtin_amdgcn_mfma_f32_16x16x32_bf16(pf[k2], b, o[et], 0, 0, 0);
            }
        }
    }

    // phase 2: degenerate rows (l == 0) attend uniformly over all mask==0 keys
    __syncthreads();
    {
        bool deg = (lacc[0] == 0.f) | (lacc[1] == 0.f) | (lacc[2] == 0.f) | (lacc[3] == 0.f);
        if (__ballot(deg) != 0ULL) {
            unsigned short* pb = (unsigned short*)((char*)kbuf + wave * 2304);  // 16 x 72 shorts
            unsigned short dsel[4];
#pragma unroll
            for (int r = 0; r < 4; r++) dsel[r] = (lacc[r] == 0.f) ? (unsigned short)0x3F80 : (unsigned short)0;
            for (int kt = 0; kt < 16; kt++) {
                unsigned long long mw2[4];
#pragma unroll
                for (int r = 0; r < 4; r++) mw2[r] = mbits[kt * Tn + qrow + r];
#pragma unroll
                for (int nt = 0; nt < 4; nt++) {
                    int bi = nt * 16 + l16;
#pragma unroll
                    for (int r = 0; r < 4; r++)
                        pb[(quad * 4 + r) * 72 + bi] = ((mw2[r] >> bi) & 1ULL) ? (unsigned short)0 : dsel[r];
                }
                bf16x8 pf[2];
#pragma unroll
                for (int k2 = 0; k2 < 2; k2++)
                    pf[k2] = *(const bf16x8*)(&pb[l16 * 72 + k2 * 32 + quad * 8]);
#pragma unroll
                for (int k2 = 0; k2 < 2; k2++)
                    lacc = __builtin_amdgcn_mfma_f32_16x16x32_bf16(pf[k2], ones, lacc, 0, 0, 0);
                const unsigned short* Vg = Vb + kt * (128 * 64);
#pragma unroll
                for (int et = 0; et < 8; et++) {
#pragma unroll
                    for (int k2 = 0; k2 < 2; k2++) {
                        bf16x8 b = *(const bf16x8*)(Vg + (et * 16 + l16) * 64 + (((k2 * 4 + quad) ^ (l16 & 7)) << 3));
                        o[et] = __builtin_amdgcn_mfma_f32_16x16x32_bf16(pf[k2], b, o[et], 0, 0, 0);
                    }
                }
            }
        }
    }

    // ---- fused output projection epilogue ----
    const int b_ = bh >> 3, h_ = bh & 7;
    {
        unsigned short* tile = (unsigned short*)((char*)vbuf + wave * 4608);  // 16 rows x 144 shorts
#pragma unroll
        for (int r = 0; r < 4; r++) {
            float inv = 1.f / lacc[r];
            int row = quad * 4 + r;
#pragma unroll
            for (int et = 0; et < 8; et++)
                tile[row * 144 + et * 16 + l16] = f2bf(o[et][r] * inv);
        }

        bf16x8 a4[4];
#pragma unroll
        for (int ks = 0; ks < 4; ks++)
            a4[ks] = *(const bf16x8*)(&tile[l16 * 144 + ks * 32 + quad * 8]);

        const unsigned short* wf = wuF + (size_t)h_ * (4 * 8 * 64 * 8);
        f32x4 acc2[8];
#pragma unroll
        for (int nt = 0; nt < 8; nt++) acc2[nt] = (f32x4){0.f, 0.f, 0.f, 0.f};
#pragma unroll
        for (int ks = 0; ks < 4; ks++) {
#pragma unroll
            for (int nt = 0; nt < 8; nt++) {
                bf16x8 b = *(const bf16x8*)(wf + ((size_t)(ks * 8 + nt) * 64 + lane) * 8);
                acc2[nt] = __builtin_amdgcn_mfma_f32_16x16x32_bf16(a4[ks], b, acc2[nt], 0, 0, 0);
            }
        }

#pragma unroll
        for (int nt = 0; nt < 8; nt++) {
            int n = nt * 16 + l16;
#pragma unroll
            for (int r = 0; r < 4; r++) {
                int q = q0 + quad * 4 + r;
                atomicAdd(&out[(size_t)(b_ * Tn + q) * Dn + n], acc2[nt][r]);
            }
        }
    }
}

extern "C" void kernel_launch(void* const* d_in, const int* in_sizes, int n_in,
                              void* d_out, int out_size, void* d_ws, size_t ws_size,
                              hipStream_t stream) {
    const float* x   = (const float*)d_in[0];
    const int* mask  = (const int*)d_in[1];
    const float* Wk  = (const float*)d_in[2];
    const float* Wq  = (const float*)d_in[3];
    const float* Wv  = (const float*)d_in[4];
    const float* Wu  = (const float*)d_in[5];
    const float* bu  = (const float*)d_in[6];
    float* out = (float*)d_out;

    char* ws = (char*)d_ws;
    unsigned short* wuF = (unsigned short*)ws; ws += (size_t)128 * 1024 * 2;
    char* Qf  = ws; ws += (size_t)64 * 1024 * 128;
    char* Kf  = ws; ws += (size_t)64 * 1024 * 128;
    unsigned short* Vtw = (unsigned short*)ws; ws += (size_t)64 * 1024 * 128 * 2;
    unsigned long long* mb = (unsigned long long*)ws; ws += (size_t)1024 * 16 * 8;

    qkv_kernel<<<dim3(64, 24), 256, 0, stream>>>(x, Wq, Wk, Wv, Wu, mask, bu, out,
                                                 wuF, mb, Qf, Kf, Vtw);
    attn_kernel<<<dim3(1024), 256, 0, stream>>>(Qf, Kf, Vtw, mb, wuF, out);
}

// Round 22
// 144.572 us; speedup vs baseline: 1.0849x; 1.0849x over previous
//
#include <hip/hip_runtime.h>

#define Bn 8
#define Hn 8
#define Tn 1024
#define Dn 128

typedef __attribute__((ext_vector_type(8))) short bf16x8;
typedef __attribute__((ext_vector_type(4))) float f32x4;

typedef __attribute__((address_space(3))) unsigned int lds_as_t;
typedef __attribute__((address_space(1))) const unsigned int glb_as_t;

static __device__ __forceinline__ void gload_lds16(const unsigned short* g, unsigned short* l) {
    __builtin_amdgcn_global_load_lds((glb_as_t*)g, (lds_as_t*)l, 16, 0, 0);
}
static __device__ __forceinline__ void gload_lds16b(const char* g, char* l) {
    __builtin_amdgcn_global_load_lds((glb_as_t*)g, (lds_as_t*)l, 16, 0, 0);
}

static __device__ __forceinline__ unsigned short f2bf(float f) {
    union { float f; unsigned int u; } v; v.f = f;
    unsigned int u = v.u;
    return (unsigned short)((u + 0x7FFFu + ((u >> 16) & 1u)) >> 16);
}
static __device__ __forceinline__ int pack_bf16_trunc(float lo, float hi) {
    union { float f; unsigned int u; } a, b;
    a.f = lo; b.f = hi;
    return (int)__builtin_amdgcn_perm(b.u, a.u, 0x07060302u);
}

// ---------------- dispatch 1: fused prep + QKV GEMM ----------------
__global__ __launch_bounds__(256, 2) void qkv_kernel(
    const float* __restrict__ x,  const float* __restrict__ Wq,
    const float* __restrict__ Wk, const float* __restrict__ Wv,
    const float* __restrict__ Wu, const int* __restrict__ mask,
    const float* __restrict__ bu, float* __restrict__ out,
    unsigned short* __restrict__ wuF, unsigned long long* __restrict__ mbits,
    char* __restrict__ Q, char* __restrict__ K, unsigned short* __restrict__ Vt)
{
    const int bx = blockIdx.x, by = blockIdx.y;
    const int tid  = threadIdx.x;
    const int wave = tid >> 6;
    const int lane = tid & 63;
    const int l16  = lane & 15;
    const int quad = lane >> 4;
    const int wm = wave & 1, wn = wave >> 1;
    const int which = by >> 3;
    const int h_ = by & 7;
    const int bid = h_ * 64 + bx;

    __shared__ __align__(16) unsigned short As[128 * 128];
    __shared__ __align__(16) unsigned short Bs[128 * 128];

    // ---- side work ----
    if (which == 0) {
        int base = (bid * 4 + wave) * 8;
#pragma unroll
        for (int i = 0; i < 8; i++) {
            int widx = base + i;
            int row = widx >> 4, kt = widx & 15;
            int v = mask[row * Tn + kt * 64 + lane];
            unsigned long long b = __ballot(v != 0);
            if (lane == 0) mbits[kt * Tn + row] = b;
        }
    } else if (which == 1) {
        if (tid < 32) {
            int id = bid * 32 + tid;
            int lane_ = id & 63;
            int fid = id >> 6;
            int nt = fid & 7, ks = (fid >> 3) & 3, h = fid >> 5;
            int row = nt * 16 + (lane_ & 15);
            int col = h * 128 + ks * 32 + (lane_ >> 4) * 8;
            const float* src = Wu + (size_t)row * 1024 + col;
            float4 f0 = *(const float4*)(src);
            float4 f1 = *(const float4*)(src + 4);
            unsigned short o[8];
            o[0] = f2bf(f0.x); o[1] = f2bf(f0.y); o[2] = f2bf(f0.z); o[3] = f2bf(f0.w);
            o[4] = f2bf(f1.x); o[5] = f2bf(f1.y); o[6] = f2bf(f1.z); o[7] = f2bf(f1.w);
            *(ushort4*)(wuF + (size_t)id * 8)     = *(ushort4*)&o[0];
            *(ushort4*)(wuF + (size_t)id * 8 + 4) = *(ushort4*)&o[4];
        }
    } else {
        int f4 = bid * 512 + tid * 2;
#pragma unroll
        for (int i = 0; i < 2; i++)
            ((float4*)out)[f4 + i] = ((const float4*)bu)[(f4 + i) & 31];
    }

    // ---- coalesced staging: fp32 -> bf16 -> swizzled LDS image ----
    const float* wsel = (which == 0) ? Wq : (which == 1) ? Wk : Wv;
    const float* Asrc = x + (size_t)(bx * 128) * 128;
    const float* Bsrc = wsel + (size_t)(h_ * 128) * 128;

#pragma unroll
    for (int it = 0; it < 16; it++) {
        int idx = it * 1024 + tid * 4;
        int row = idx >> 7, col = idx & 127;
        int dst = row * 128 + ((((col >> 3) ^ (row & 15)) << 3) | (col & 7));
        float4 fa = *(const float4*)(Asrc + idx);
        ushort4 oa;
        oa.x = f2bf(fa.x); oa.y = f2bf(fa.y); oa.z = f2bf(fa.z); oa.w = f2bf(fa.w);
        *(ushort4*)(&As[dst]) = oa;
        float4 fb = *(const float4*)(Bsrc + idx);
        ushort4 ob;
        ob.x = f2bf(fb.x); ob.y = f2bf(fb.y); ob.z = f2bf(fb.z); ob.w = f2bf(fb.w);
        *(ushort4*)(&Bs[dst]) = ob;
    }
    __syncthreads();

    // ---- MFMA body ----
    bf16x8 a[4][4];
#pragma unroll
    for (int mt = 0; mt < 4; mt++) {
        int row = wm * 64 + mt * 16 + l16;
#pragma unroll
        for (int ks = 0; ks < 4; ks++)
            a[mt][ks] = *(const bf16x8*)(&As[row * 128 + (((ks * 4 + quad) ^ (row & 15)) << 3)]);
    }

    f32x4 acc[4][4];
#pragma unroll
    for (int nt = 0; nt < 4; nt++) {
        int row = wn * 64 + nt * 16 + l16;
        bf16x8 b4[4];
#pragma unroll
        for (int ks = 0; ks < 4; ks++)
            b4[ks] = *(const bf16x8*)(&Bs[row * 128 + (((ks * 4 + quad) ^ (row & 15)) << 3)]);
#pragma unroll
        for (int mt = 0; mt < 4; mt++) {
            f32x4 c = {0.f, 0.f, 0.f, 0.f};
#pragma unroll
            for (int ks = 0; ks < 4; ks++)
                c = __builtin_amdgcn_mfma_f32_16x16x32_bf16(a[mt][ks], b4[ks], c, 0, 0, 0);
            acc[mt][nt] = c;
        }
    }

    const int b_ = bx >> 3;
    if (which < 2) {
        __syncthreads();
        char* escr = (char*)As;
#pragma unroll
        for (int mt = 0; mt < 4; mt++) {
#pragma unroll
            for (int nt = 0; nt < 4; nt++) {
                int w = __builtin_amdgcn_cvt_pk_fp8_f32(acc[mt][nt][0], acc[mt][nt][1], 0, false);
                w = __builtin_amdgcn_cvt_pk_fp8_f32(acc[mt][nt][2], acc[mt][nt][3], w, true);
                int col = wn * 64 + nt * 16 + l16;
#pragma unroll
                for (int r = 0; r < 4; r++)
                    escr[(wm * 64 + mt * 16 + quad * 4 + r) * 144 + col] = (char)(w >> (8 * r));
            }
        }
        __syncthreads();
        int row = tid >> 1;
        int t_in = (bx & 7) * 128 + row;
        char* dst = (which == 0) ? Q : K;
        size_t rowbase = ((size_t)((b_ * Hn + h_) * Tn + t_in)) * 128;
#pragma unroll
        for (int i = 0; i < 4; i++) {
            int c = (tid & 1) * 4 + i;
            int4 v = *(const int4*)(escr + row * 144 + c * 16);
            int cc = (which == 1) ? (c ^ (row & 7)) : c;
            *(int4*)(dst + rowbase + cc * 16) = v;
        }
    } else {
#pragma unroll
        for (int mt = 0; mt < 4; mt++) {
            int m_base = bx * 128 + wm * 64 + mt * 16 + quad * 4;
            int t0 = m_base & 1023;
#pragma unroll
            for (int nt = 0; nt < 4; nt++) {
                int e_ = wn * 64 + nt * 16 + l16;
                int kt_ = t0 >> 6, tc0 = t0 & 63;
                size_t off = ((((size_t)(b_ * Hn + h_) * 16 + kt_) * 128 + e_) << 6)
                           + ((((tc0 >> 3) ^ (e_ & 7)) << 3) | (tc0 & 7));
                ushort4 v4;
                v4.x = f2bf(acc[mt][nt][0]); v4.y = f2bf(acc[mt][nt][1]);
                v4.z = f2bf(acc[mt][nt][2]); v4.w = f2bf(acc[mt][nt][3]);
                *(ushort4*)(Vt + off) = v4;
            }
        }
    }
}

// ---------------- dispatch 2: flash attention + fused outproj (R20) ----------------
// XCD-aware remap: bh = id&63, t = id>>6, qb = t<4 ? t : 11-t.
// Same-bh blocks all have id%8 == bh%8 -> same XCD -> that bh's K/V stays
// L2-resident (FETCH 68->17 MB measured). Co-resident pair (id, id+256) has
// qb pairs (0,7),(1,6),(2,5),(3,4) -> every pair sums 18 iterations.
__global__ __launch_bounds__(256, 2) void attn_kernel(
    const char* __restrict__ Q,               // fp8 [64][1024][128] plain
    const char* __restrict__ K,               // fp8 [64][1024][128] chunk swizzle c^(t&7)
    const unsigned short* __restrict__ Vt,    // bf16 [64][16][128][64] tiled+swizzled
    const unsigned long long* __restrict__ mbits, // [16][1024] transposed
    const unsigned short* __restrict__ wuF,   // [((h*4+ks)*8+nt)*64+lane][8]
    float* __restrict__ out)                  // [8192][128] fp32, bias-preset
{
    const int id   = blockIdx.x;
    const int bh   = id & 63;
    const int t_   = id >> 6;
    const int qb   = (t_ < 4) ? t_ : 11 - t_;
    const int wave = threadIdx.x >> 6;
    const int lane = threadIdx.x & 63;
    const int l16  = lane & 15;
    const int quad = lane >> 4;

    __shared__ __align__(16) char kbuf[2][64 * 128];            // 8 KB each
    __shared__ __align__(16) unsigned short vbuf[2][128 * 64];  // 16 KB each

    const char* Qb = Q  + (size_t)bh * Tn * Dn;
    const char* Kb = K  + (size_t)bh * Tn * Dn;
    const unsigned short* Vb = Vt + (size_t)bh * (16 * 128 * 64);

    const int blkkt = 2 * qb + 1;
    const int q0w   = qb * 128 + wave * 32;
    const int q0s[2] = { q0w, q0w + 16 };
    const int wkmax = (q0w + 31) >> 6;

    long qf[2][4];
#pragma unroll
    for (int st = 0; st < 2; st++)
#pragma unroll
        for (int ks = 0; ks < 4; ks++)
            qf[st][ks] = *(const long*)(Qb + (size_t)(q0s[st] + l16) * 128 + ks * 32 + quad * 8);

    bf16x8 ones;
#pragma unroll
    for (int j = 0; j < 8; j++) ones[j] = (short)0x3F80;

    f32x4 o[2][8];
#pragma unroll
    for (int st = 0; st < 2; st++)
#pragma unroll
        for (int et = 0; et < 8; et++) o[st][et] = (f32x4){0.f, 0.f, 0.f, 0.f};
    f32x4 lacc[2];
    lacc[0] = (f32x4){0.f, 0.f, 0.f, 0.f};
    lacc[1] = (f32x4){0.f, 0.f, 0.f, 0.f};

    const float SL = 0.12752041570284543f;  // 1/sqrt(128) * log2(e)

    const int idx0 = (l16 << 2) + ((quad & 1) << 7);
    const int idx1 = idx0 + 64;
    const bool hiQ = (quad >> 1) != 0;

#pragma unroll
    for (int i = 0; i < 2; i++) {
        int base = (wave * 2 + i) * 1024;
        gload_lds16b(Kb + base + lane * 16, &kbuf[0][base]);
    }
#pragma unroll
    for (int i = 0; i < 4; i++) {
        int base = (wave * 4 + i) * 512;
        gload_lds16(Vb + base + lane * 8, &vbuf[0][base]);
    }

    for (int kt = 0; kt <= blkkt; kt++) {
        const int cur = kt & 1;
        __syncthreads();

        if (kt < blkkt) {
            const char* Kg = Kb + (kt + 1) * (64 * 128);
            const unsigned short* Vg = Vb + (kt + 1) * (128 * 64);
#pragma unroll
            for (int i = 0; i < 2; i++) {
                int base = (wave * 2 + i) * 1024;
                gload_lds16b(Kg + base + lane * 16, &kbuf[cur ^ 1][base]);
            }
#pragma unroll
            for (int i = 0; i < 4; i++) {
                int base = (wave * 4 + i) * 512;
                gload_lds16(Vg + base + lane * 8, &vbuf[cur ^ 1][base]);
            }
        }

        if (kt <= wkmax) {
            unsigned long long mw[2];
            mw[0] = mbits[kt * Tn + q0s[0] + l16];
            mw[1] = mbits[kt * Tn + q0s[1] + l16];

            f32x4 s[2][4];
#pragma unroll
            for (int nt = 0; nt < 4; nt++) {
                int row = nt * 16 + l16;
                long a4[4];
#pragma unroll
                for (int ks = 0; ks < 4; ks++) {
                    int c = ks * 2 + (quad >> 1);
                    a4[ks] = *(const long*)(&kbuf[cur][row * 128 + (((c ^ (row & 7)) << 4) | ((quad & 1) << 3))]);
                }
#pragma unroll
                for (int st = 0; st < 2; st++) {
                    f32x4 c = {0.f, 0.f, 0.f, 0.f};
#pragma unroll
                    for (int ks = 0; ks < 4; ks++)
                        c = __builtin_amdgcn_mfma_f32_16x16x32_fp8_fp8(a4[ks], qf[st][ks], c, 0, 0, 0);
                    s[st][nt] = c;
                }
            }

            const int kc0 = kt * 64;
            bf16x8 pf[2][2];
#pragma unroll
            for (int st = 0; st < 2; st++) {
                const int qglob = q0s[st] + l16;
                int w[4][2];
#pragma unroll
                for (int nt = 0; nt < 4; nt++) {
                    float pv[4];
#pragma unroll
                    for (int r = 0; r < 4; r++) {
                        int bit = nt * 16 + quad * 4 + r;
                        bool live = ((mw[st] >> bit) & 1ULL) && (kc0 + bit <= qglob);
                        pv[r] = live ? __builtin_amdgcn_exp2f(s[st][nt][r] * SL) : 0.f;
                    }
                    w[nt][0] = pack_bf16_trunc(pv[0], pv[1]);
                    w[nt][1] = pack_bf16_trunc(pv[2], pv[3]);
                }
#pragma unroll
                for (int k2 = 0; k2 < 2; k2++) {
                    union { int i[4]; bf16x8 v; } u;
#pragma unroll
                    for (int d = 0; d < 4; d++) {
                        int idx = (d < 2) ? idx0 : idx1;
                        int va = __builtin_amdgcn_ds_bpermute(idx, w[2 * k2][d & 1]);
                        int vb = __builtin_amdgcn_ds_bpermute(idx, w[2 * k2 + 1][d & 1]);
                        u.i[d] = hiQ ? vb : va;
                    }
                    pf[st][k2] = u.v;
                }
            }

#pragma unroll
            for (int st = 0; st < 2; st++)
#pragma unroll
                for (int k2 = 0; k2 < 2; k2++)
                    lacc[st] = __builtin_amdgcn_mfma_f32_16x16x32_bf16(pf[st][k2], ones, lacc[st], 0, 0, 0);

#pragma unroll
            for (int et = 0; et < 8; et++) {
                int row = et * 16 + l16;
#pragma unroll
                for (int k2 = 0; k2 < 2; k2++) {
                    bf16x8 b = *(const bf16x8*)(&vbuf[cur][row * 64 + (((k2 * 4 + quad) ^ (l16 & 7)) << 3)]);
                    o[0][et] = __builtin_amdgcn_mfma_f32_16x16x32_bf16(pf[0][k2], b, o[0][et], 0, 0, 0);
                    o[1][et] = __builtin_amdgcn_mfma_f32_16x16x32_bf16(pf[1][k2], b, o[1][et], 0, 0, 0);
                }
            }
        }
    }

    // phase 2: degenerate rows (l == 0) attend uniformly over all mask==0 keys
    __syncthreads();
    {
        bool deg = false;
#pragma unroll
        for (int st = 0; st < 2; st++)
#pragma unroll
            for (int r = 0; r < 4; r++) deg |= (lacc[st][r] == 0.f);
        if (__ballot(deg) != 0ULL) {
            unsigned short* pb = (unsigned short*)((char*)kbuf + wave * 2304);  // 16 x 72 shorts
            unsigned short dsel[2][4];
#pragma unroll
            for (int st = 0; st < 2; st++)
#pragma unroll
                for (int r = 0; r < 4; r++)
                    dsel[st][r] = (lacc[st][r] == 0.f) ? (unsigned short)0x3F80 : (unsigned short)0;
            for (int kt = 0; kt < 16; kt++) {
#pragma unroll
                for (int st = 0; st < 2; st++) {
                    int qrow = q0s[st] + quad * 4;
                    unsigned long long mw2[4];
#pragma unroll
                    for (int r = 0; r < 4; r++) mw2[r] = mbits[kt * Tn + qrow + r];
#pragma unroll
                    for (int nt = 0; nt < 4; nt++) {
                        int bi = nt * 16 + l16;
#pragma unroll
                        for (int r = 0; r < 4; r++)
                            pb[(quad * 4 + r) * 72 + bi] = ((mw2[r] >> bi) & 1ULL) ? (unsigned short)0 : dsel[st][r];
                    }
                    bf16x8 pf[2];
#pragma unroll
                    for (int k2 = 0; k2 < 2; k2++)
                        pf[k2] = *(const bf16x8*)(&pb[l16 * 72 + k2 * 32 + quad * 8]);
#pragma unroll
                    for (int k2 = 0; k2 < 2; k2++)
                        lacc[st] = __builtin_amdgcn_mfma_f32_16x16x32_bf16(pf[k2], ones, lacc[st], 0, 0, 0);
                    const unsigned short* Vg = Vb + kt * (128 * 64);
#pragma unroll
                    for (int et = 0; et < 8; et++) {
#pragma unroll
                        for (int k2 = 0; k2 < 2; k2++) {
                            bf16x8 b = *(const bf16x8*)(Vg + (et * 16 + l16) * 64 + (((k2 * 4 + quad) ^ (l16 & 7)) << 3));
                            o[st][et] = __builtin_amdgcn_mfma_f32_16x16x32_bf16(pf[k2], b, o[st][et], 0, 0, 0);
                        }
                    }
                }
            }
        }
    }

    // fused output projection epilogue
    const int b_ = bh >> 3, h_ = bh & 7;
    const unsigned short* wf = wuF + (size_t)h_ * (4 * 8 * 64 * 8);
#pragma unroll
    for (int st = 0; st < 2; st++) {
        unsigned short* tile = (unsigned short*)((char*)vbuf + wave * 4608);  // 16 x 144 shorts
#pragma unroll
        for (int r = 0; r < 4; r++) {
            float inv = 1.f / lacc[st][r];
            int row = quad * 4 + r;
#pragma unroll
            for (int et = 0; et < 8; et++)
                tile[row * 144 + et * 16 + l16] = f2bf(o[st][et][r] * inv);
        }

        bf16x8 a4[4];
#pragma unroll
        for (int ks = 0; ks < 4; ks++)
            a4[ks] = *(const bf16x8*)(&tile[l16 * 144 + ks * 32 + quad * 8]);

        f32x4 acc2[8];
#pragma unroll
        for (int nt = 0; nt < 8; nt++) acc2[nt] = (f32x4){0.f, 0.f, 0.f, 0.f};
#pragma unroll
        for (int ks = 0; ks < 4; ks++) {
#pragma unroll
            for (int nt = 0; nt < 8; nt++) {
                bf16x8 b = *(const bf16x8*)(wf + ((size_t)(ks * 8 + nt) * 64 + lane) * 8);
                acc2[nt] = __builtin_amdgcn_mfma_f32_16x16x32_bf16(a4[ks], b, acc2[nt], 0, 0, 0);
            }
        }

#pragma unroll
        for (int nt = 0; nt < 8; nt++) {
            int n = nt * 16 + l16;
#pragma unroll
            for (int r = 0; r < 4; r++) {
                int q = q0s[st] + quad * 4 + r;
                atomicAdd(&out[(size_t)(b_ * Tn + q) * Dn + n], acc2[nt][r]);
            }
        }
    }
}

extern "C" void kernel_launch(void* const* d_in, const int* in_sizes, int n_in,
                              void* d_out, int out_size, void* d_ws, size_t ws_size,
                              hipStream_t stream) {
    const float* x   = (const float*)d_in[0];
    const int* mask  = (const int*)d_in[1];
    const float* Wk  = (const float*)d_in[2];
    const float* Wq  = (const float*)d_in[3];
    const float* Wv  = (const float*)d_in[4];
    const float* Wu  = (const float*)d_in[5];
    const float* bu  = (const float*)d_in[6];
    float* out = (float*)d_out;

    char* ws = (char*)d_ws;
    unsigned short* wuF = (unsigned short*)ws; ws += (size_t)128 * 1024 * 2;
    char* Qf  = ws; ws += (size_t)64 * 1024 * 128;
    char* Kf  = ws; ws += (size_t)64 * 1024 * 128;
    unsigned short* Vtw = (unsigned short*)ws; ws += (size_t)64 * 1024 * 128 * 2;
    unsigned long long* mb = (unsigned long long*)ws; ws += (size_t)1024 * 16 * 8;

    qkv_kernel<<<dim3(64, 24), 256, 0, stream>>>(x, Wq, Wk, Wv, Wu, mask, bu, out,
                                                 wuF, mb, Qf, Kf, Vtw);
    attn_kernel<<<dim3(512), 256, 0, stream>>>(Qf, Kf, Vtw, mb, wuF, out);
}